// Round 1
// baseline (615.385 us; speedup 1.0000x reference)
//
#include <hip/hip_runtime.h>
#include <hip/hip_bf16.h>

// Problem constants (B=2, L=2048, D=2048, E=8, Dg=256, k=2)
#define T_TOK 4096          // B*L tokens
#define DIM   2048          // D
#define NEXP  8             // E
#define DG    256           // Dg
#define TOPK  2

// GEMM tiling
#define BM 64
#define BN 64
#define BK 16

#define NROWS  (T_TOK*TOPK + NEXP*BM)    // 8704: padded row capacity
#define NBLK_M (T_TOK*TOPK/BM + NEXP)    // 136: upper bound on padded row-blocks

// ---------------------------------------------------------------------------
// Kernel 1: gate scores + top-2. One wave per token (4 tokens / 256-thr block).
// S[t,e] = sigmoid(x[t] . Wg[e]); top-2 with lowest-index tie-break (matches
// jax.lax.top_k stability; sigmoid is monotonic so ties match logit ties).
// ---------------------------------------------------------------------------
__global__ __launch_bounds__(256) void gate_kernel(const float* __restrict__ x,
                                                   const float* __restrict__ Wg,
                                                   int* __restrict__ gidx,
                                                   float* __restrict__ gval)
{
    int token = blockIdx.x * 4 + (threadIdx.x >> 6);
    int lane  = threadIdx.x & 63;
    const float* xr = x + (size_t)token * DIM;

    float xv[DIM / 64];
#pragma unroll
    for (int i = 0; i < DIM / 64; i++) xv[i] = xr[lane + 64 * i];

    float s[NEXP];
#pragma unroll
    for (int e = 0; e < NEXP; e++) {
        const float* wr = Wg + e * DIM;
        float acc = 0.0f;
#pragma unroll
        for (int i = 0; i < DIM / 64; i++) acc += xv[i] * wr[lane + 64 * i];
#pragma unroll
        for (int m = 1; m < 64; m <<= 1) acc += __shfl_xor(acc, m, 64);
        s[e] = acc;
    }

    if (lane == 0) {
        float sg[NEXP];
#pragma unroll
        for (int e = 0; e < NEXP; e++) sg[e] = 1.0f / (1.0f + expf(-s[e]));
        int i0 = 0;
#pragma unroll
        for (int e = 1; e < NEXP; e++) if (sg[e] > sg[i0]) i0 = e;   // strict >: lowest index wins
        int i1 = (i0 == 0) ? 1 : 0;
#pragma unroll
        for (int e = 0; e < NEXP; e++) if (e != i0 && e != i1 && sg[e] > sg[i1]) i1 = e;
        gidx[2 * token + 0] = i0;
        gidx[2 * token + 1] = i1;
        gval[2 * token + 0] = sg[i0];
        gval[2 * token + 1] = sg[i1];
    }
}

// ---------------------------------------------------------------------------
// Kernel 2: bucket (token,slot) rows by expert, pad each segment to BM rows.
// Single block; E=8 so this is trivial. rowtok = -1 marks pad rows.
// ---------------------------------------------------------------------------
__global__ __launch_bounds__(256) void bucket_kernel(const int* __restrict__ gidx,
                                                     const float* __restrict__ gval,
                                                     int* __restrict__ rowtok,
                                                     float* __restrict__ rowgate,
                                                     int* __restrict__ seg_off)
{
    __shared__ int cnt[NEXP];
    __shared__ int cur[NEXP];
    int tid = threadIdx.x;
    if (tid < NEXP) cnt[tid] = 0;
    __syncthreads();

    for (int t = tid; t < T_TOK; t += 256) {
        atomicAdd(&cnt[gidx[2 * t + 0]], 1);
        atomicAdd(&cnt[gidx[2 * t + 1]], 1);
    }
    __syncthreads();

    if (tid == 0) {
        int o = 0;
        for (int e = 0; e < NEXP; e++) {
            seg_off[e] = o;
            cur[e] = o;
            o += ((cnt[e] + BM - 1) / BM) * BM;   // pad to BM multiple
        }
        seg_off[NEXP] = o;
    }
    __syncthreads();

    for (int r = tid; r < NROWS; r += 256) rowtok[r] = -1;
    __syncthreads();

    for (int t = tid; t < T_TOK; t += 256) {
        for (int s = 0; s < TOPK; s++) {
            int e = gidx[2 * t + s];
            int p = atomicAdd(&cur[e], 1);
            rowtok[p]  = t;
            rowgate[p] = gval[2 * t + s];
        }
    }
}

// ---------------------------------------------------------------------------
// Kernel 3: down = scatter-add over experts of  gate * (x[t] @ Wd[e]^T)
// Grouped GEMM: A = gathered gate-scaled x rows [rows x 2048],
//               B = Wd[e] (row g contiguous in d) -> C [rows x 256].
// Tile 64x64, BK=16. LDS k-major, float4 LDS reads (conflict-free).
// ---------------------------------------------------------------------------
__global__ __launch_bounds__(256) void down_kernel(const float* __restrict__ x,
                                                   const float* __restrict__ Wd,
                                                   const int* __restrict__ rowtok,
                                                   const float* __restrict__ rowgate,
                                                   const int* __restrict__ seg_off,
                                                   float* __restrict__ down)
{
    __shared__ float As[BK][BM];
    __shared__ float Bs[BK][BN];

    int row0 = blockIdx.x * BM;
    if (row0 >= seg_off[NEXP]) return;
    int e = 0;
    while (row0 >= seg_off[e + 1]) ++e;   // segments are BM-padded: block is within one expert

    int g0  = blockIdx.y * BN;
    int tid = threadIdx.x;
    int lrow = tid >> 2;          // 0..63 : A row / B row within tile
    int lkq  = (tid & 3) * 4;     // 0,4,8,12 : k sub-offset (float4)

    int   t  = rowtok[row0 + lrow];
    float gv = (t >= 0) ? rowgate[row0 + lrow] : 0.0f;
    const float* arow = x + (size_t)(t >= 0 ? t : 0) * DIM;
    const float* brow = Wd + (size_t)e * DG * DIM + (size_t)(g0 + lrow) * DIM;

    int tx = tid & 15, ty = tid >> 4;
    float acc[4][4];
#pragma unroll
    for (int i = 0; i < 4; i++)
#pragma unroll
        for (int j = 0; j < 4; j++) acc[i][j] = 0.0f;

    for (int k0 = 0; k0 < DIM; k0 += BK) {
        float4 av = *(const float4*)(arow + k0 + lkq);
        float4 bv = *(const float4*)(brow + k0 + lkq);
        As[lkq + 0][lrow] = av.x * gv;
        As[lkq + 1][lrow] = av.y * gv;
        As[lkq + 2][lrow] = av.z * gv;
        As[lkq + 3][lrow] = av.w * gv;
        Bs[lkq + 0][lrow] = bv.x;
        Bs[lkq + 1][lrow] = bv.y;
        Bs[lkq + 2][lrow] = bv.z;
        Bs[lkq + 3][lrow] = bv.w;
        __syncthreads();
#pragma unroll
        for (int kk = 0; kk < BK; kk++) {
            float4 a = *(const float4*)&As[kk][ty * 4];
            float4 b = *(const float4*)&Bs[kk][tx * 4];
            acc[0][0] += a.x * b.x; acc[0][1] += a.x * b.y; acc[0][2] += a.x * b.z; acc[0][3] += a.x * b.w;
            acc[1][0] += a.y * b.x; acc[1][1] += a.y * b.y; acc[1][2] += a.y * b.z; acc[1][3] += a.y * b.w;
            acc[2][0] += a.z * b.x; acc[2][1] += a.z * b.y; acc[2][2] += a.z * b.z; acc[2][3] += a.z * b.w;
            acc[3][0] += a.w * b.x; acc[3][1] += a.w * b.y; acc[3][2] += a.w * b.z; acc[3][3] += a.w * b.w;
        }
        __syncthreads();
    }

#pragma unroll
    for (int i = 0; i < 4; i++) {
        int tt = rowtok[row0 + ty * 4 + i];
        if (tt >= 0) {
#pragma unroll
            for (int j = 0; j < 4; j++)
                atomicAdd(&down[(size_t)tt * DG + g0 + tx * 4 + j], acc[i][j]);
        }
    }
}

// ---------------------------------------------------------------------------
// Kernel 4: out = scatter-add over experts of  gate * (down[t] @ Wu[e]^T)
// Same structure; A = gathered gate-scaled down rows [rows x 256],
// B = Wu[e] (row d contiguous in g) -> C [rows x 2048].
// ---------------------------------------------------------------------------
__global__ __launch_bounds__(256) void up_kernel(const float* __restrict__ down,
                                                 const float* __restrict__ Wu,
                                                 const int* __restrict__ rowtok,
                                                 const float* __restrict__ rowgate,
                                                 const int* __restrict__ seg_off,
                                                 float* __restrict__ out)
{
    __shared__ float As[BK][BM];
    __shared__ float Bs[BK][BN];

    int row0 = blockIdx.x * BM;
    if (row0 >= seg_off[NEXP]) return;
    int e = 0;
    while (row0 >= seg_off[e + 1]) ++e;

    int d0  = blockIdx.y * BN;
    int tid = threadIdx.x;
    int lrow = tid >> 2;
    int lkq  = (tid & 3) * 4;

    int   t  = rowtok[row0 + lrow];
    float gv = (t >= 0) ? rowgate[row0 + lrow] : 0.0f;
    const float* arow = down + (size_t)(t >= 0 ? t : 0) * DG;
    const float* brow = Wu + (size_t)e * DIM * DG + (size_t)(d0 + lrow) * DG;

    int tx = tid & 15, ty = tid >> 4;
    float acc[4][4];
#pragma unroll
    for (int i = 0; i < 4; i++)
#pragma unroll
        for (int j = 0; j < 4; j++) acc[i][j] = 0.0f;

    for (int k0 = 0; k0 < DG; k0 += BK) {
        float4 av = *(const float4*)(arow + k0 + lkq);
        float4 bv = *(const float4*)(brow + k0 + lkq);
        As[lkq + 0][lrow] = av.x * gv;
        As[lkq + 1][lrow] = av.y * gv;
        As[lkq + 2][lrow] = av.z * gv;
        As[lkq + 3][lrow] = av.w * gv;
        Bs[lkq + 0][lrow] = bv.x;
        Bs[lkq + 1][lrow] = bv.y;
        Bs[lkq + 2][lrow] = bv.z;
        Bs[lkq + 3][lrow] = bv.w;
        __syncthreads();
#pragma unroll
        for (int kk = 0; kk < BK; kk++) {
            float4 a = *(const float4*)&As[kk][ty * 4];
            float4 b = *(const float4*)&Bs[kk][tx * 4];
            acc[0][0] += a.x * b.x; acc[0][1] += a.x * b.y; acc[0][2] += a.x * b.z; acc[0][3] += a.x * b.w;
            acc[1][0] += a.y * b.x; acc[1][1] += a.y * b.y; acc[1][2] += a.y * b.z; acc[1][3] += a.y * b.w;
            acc[2][0] += a.z * b.x; acc[2][1] += a.z * b.y; acc[2][2] += a.z * b.z; acc[2][3] += a.z * b.w;
            acc[3][0] += a.w * b.x; acc[3][1] += a.w * b.y; acc[3][2] += a.w * b.z; acc[3][3] += a.w * b.w;
        }
        __syncthreads();
    }

#pragma unroll
    for (int i = 0; i < 4; i++) {
        int tt = rowtok[row0 + ty * 4 + i];
        if (tt >= 0) {
#pragma unroll
            for (int j = 0; j < 4; j++)
                atomicAdd(&out[(size_t)tt * DIM + d0 + tx * 4 + j], acc[i][j]);
        }
    }
}

// ---------------------------------------------------------------------------
// Workspace layout (float elements):
//   [0)        gidx    : 2*T ints        (8192)
//   [8192)     gval    : 2*T floats      (8192)
//   [16384)    rowtok  : NROWS ints      (8704)
//   [25088)    rowgate : NROWS floats    (8704)
//   [33792)    seg_off : E+1 ints        (9, padded)
//   [34816)    down    : T*DG floats     (1048576)
// Total ~4.3 MB. down and d_out are accumulated into -> zeroed each launch.
// ---------------------------------------------------------------------------
extern "C" void kernel_launch(void* const* d_in, const int* in_sizes, int n_in,
                              void* d_out, int out_size, void* d_ws, size_t ws_size,
                              hipStream_t stream) {
    const float* x  = (const float*)d_in[0];
    const float* Wg = (const float*)d_in[1];
    const float* Wd = (const float*)d_in[2];
    const float* Wu = (const float*)d_in[3];
    float* out = (float*)d_out;

    float* wsf     = (float*)d_ws;
    int*   gidx    = (int*)wsf;
    float* gval    = wsf + 8192;
    int*   rowtok  = (int*)(wsf + 16384);
    float* rowgate = wsf + 25088;
    int*   seg_off = (int*)(wsf + 33792);
    float* down    = wsf + 34816;

    hipMemsetAsync(down, 0, (size_t)T_TOK * DG * sizeof(float), stream);
    hipMemsetAsync(out, 0, (size_t)out_size * sizeof(float), stream);

    gate_kernel<<<T_TOK / 4, 256, 0, stream>>>(x, Wg, gidx, gval);
    bucket_kernel<<<1, 256, 0, stream>>>(gidx, gval, rowtok, rowgate, seg_off);
    down_kernel<<<dim3(NBLK_M, DG / BN), 256, 0, stream>>>(x, Wd, rowtok, rowgate, seg_off, down);
    up_kernel<<<dim3(NBLK_M, DIM / BN), 256, 0, stream>>>(down, Wu, rowtok, rowgate, seg_off, out);
}

// Round 2
// 273.579 us; speedup vs baseline: 2.2494x; 2.2494x over previous
//
#include <hip/hip_runtime.h>
#include <hip/hip_bf16.h>
#include <stdint.h>

// Problem constants (B=2, L=2048, D=2048, E=8, Dg=256, k=2)
#define T_TOK 4096
#define DIM   2048
#define NEXP  8
#define DG    256
#define TOPK  2

// GEMM tiling: block tile 64(M) x 128(N), BK=32, 4 waves of 32x64 each
#define BM 64
#define BN 128
#define BK 32
#define NROWS  (T_TOK*TOPK + NEXP*BM)   // 8704 padded row capacity
#define NBLK_M (NROWS/BM)               // 136 M-blocks

typedef __attribute__((ext_vector_type(8))) short short8;
typedef __attribute__((ext_vector_type(4))) float f32x4;

static __device__ __forceinline__ short f2bf(float f) {
    union { float f; uint32_t u; } v{f};
    uint32_t r = v.u + 0x7fffu + ((v.u >> 16) & 1u);   // RNE
    return (short)(r >> 16);
}
static __device__ __forceinline__ float b2f(short s) {
    union { uint32_t u; float f; } v{((uint32_t)(unsigned short)s) << 16};
    return v.f;
}

#define GLD16(g, l) \
    __builtin_amdgcn_global_load_lds((const __attribute__((address_space(1))) void*)(g), \
                                     (__attribute__((address_space(3))) void*)(l), 16, 0, 0)

// ---------------------------------------------------------------------------
// fp32 -> bf16 conversion, float4-vectorized (n4 = count/4)
// ---------------------------------------------------------------------------
__global__ __launch_bounds__(256) void conv_kernel(const float* __restrict__ s,
                                                   short* __restrict__ d, int n4)
{
    int i = blockIdx.x * 256 + threadIdx.x;
    if (i < n4) {
        float4 v = ((const float4*)s)[i];
        short4 o;
        o.x = f2bf(v.x); o.y = f2bf(v.y); o.z = f2bf(v.z); o.w = f2bf(v.w);
        ((short4*)d)[i] = o;
    }
}

// ---------------------------------------------------------------------------
// Gate: S = sigmoid(x @ Wg^T) fp32, top-2 lowest-index tie-break.
// One wave per token.
// ---------------------------------------------------------------------------
__global__ __launch_bounds__(256) void gate_kernel(const float* __restrict__ x,
                                                   const float* __restrict__ Wg,
                                                   int* __restrict__ gidx,
                                                   float* __restrict__ gval)
{
    int token = blockIdx.x * 4 + (threadIdx.x >> 6);
    int lane  = threadIdx.x & 63;
    const float* xr = x + (size_t)token * DIM;

    float xv[DIM / 64];
#pragma unroll
    for (int i = 0; i < DIM / 64; i++) xv[i] = xr[lane + 64 * i];

    float s[NEXP];
#pragma unroll
    for (int e = 0; e < NEXP; e++) {
        const float* wr = Wg + e * DIM;
        float acc = 0.0f;
#pragma unroll
        for (int i = 0; i < DIM / 64; i++) acc += xv[i] * wr[lane + 64 * i];
#pragma unroll
        for (int m = 1; m < 64; m <<= 1) acc += __shfl_xor(acc, m, 64);
        s[e] = acc;
    }

    if (lane == 0) {
        float sg[NEXP];
#pragma unroll
        for (int e = 0; e < NEXP; e++) sg[e] = 1.0f / (1.0f + expf(-s[e]));
        int i0 = 0;
#pragma unroll
        for (int e = 1; e < NEXP; e++) if (sg[e] > sg[i0]) i0 = e;
        int i1 = (i0 == 0) ? 1 : 0;
#pragma unroll
        for (int e = 0; e < NEXP; e++) if (e != i0 && e != i1 && sg[e] > sg[i1]) i1 = e;
        gidx[2 * token + 0] = i0;
        gidx[2 * token + 1] = i1;
        gval[2 * token + 0] = sg[i0];
        gval[2 * token + 1] = sg[i1];
    }
}

// ---------------------------------------------------------------------------
// Bucket rows by expert (segments padded to BM); record forward map rowtok
// and inverse map rowpos[2t+s] = row index.
// ---------------------------------------------------------------------------
__global__ __launch_bounds__(256) void bucket_kernel(const int* __restrict__ gidx,
                                                     int* __restrict__ rowtok,
                                                     int* __restrict__ rowpos,
                                                     int* __restrict__ seg_off)
{
    __shared__ int cnt[NEXP];
    __shared__ int cur[NEXP];
    int tid = threadIdx.x;
    if (tid < NEXP) cnt[tid] = 0;
    __syncthreads();

    for (int t = tid; t < T_TOK; t += 256) {
        atomicAdd(&cnt[gidx[2 * t + 0]], 1);
        atomicAdd(&cnt[gidx[2 * t + 1]], 1);
    }
    __syncthreads();

    if (tid == 0) {
        int o = 0;
        for (int e = 0; e < NEXP; e++) {
            seg_off[e] = o;
            cur[e] = o;
            o += ((cnt[e] + BM - 1) / BM) * BM;
        }
        seg_off[NEXP] = o;
    }
    __syncthreads();

    for (int r = tid; r < NROWS; r += 256) rowtok[r] = -1;
    __syncthreads();

    for (int t = tid; t < T_TOK; t += 256) {
        for (int s = 0; s < TOPK; s++) {
            int e = gidx[2 * t + s];
            int p = atomicAdd(&cur[e], 1);
            rowtok[p] = t;
            rowpos[2 * t + s] = p;
        }
    }
}

// ---------------------------------------------------------------------------
// Grouped GEMM (bf16 MFMA): C[row][n] = sum_k A[rowtok[row]][k] * B[e][n][k]
//   A: [T?][K] bf16 token rows (gathered per-lane via rowtok)
//   B: [E][N_total][K] bf16, k-contiguous; this block covers n0..n0+BN
//   C: [NROWS][Ntot] bf16 (unscaled per-row result)
// Staging via global_load_lds width=16 (per-lane global addr, wave-uniform
// LDS base). 16B-chunk XOR swizzle (chunk = q ^ ((m>>1)&3)) makes the
// ds_read_b128 fragment reads 2-way (free).
// ---------------------------------------------------------------------------
template<int K, int Ntot>
__global__ __launch_bounds__(256) void gemm_kernel(const short* __restrict__ A,
                                                   const short* __restrict__ B,
                                                   const int* __restrict__ rowtok,
                                                   const int* __restrict__ seg_off,
                                                   short* __restrict__ C)
{
    __shared__ short As[BM][BK];   // 4 KB
    __shared__ short Bs[BN][BK];   // 8 KB

    int row0 = blockIdx.x * BM;
    int total = seg_off[NEXP];
    if (row0 >= total) return;
    int e = 0;
    while (row0 >= seg_off[e + 1]) ++e;   // BM-padded segments: block in one expert
    int n0 = blockIdx.y * BN;

    int tid = threadIdx.x;
    int w = tid >> 6, l = tid & 63;

    // ---- staging addresses (fixed per lane; advance by BK per step) ----
    int ar = (w << 4) + (l >> 2);              // A row in tile (0..63)
    int achunk = (l & 3) ^ ((l >> 3) & 3);     // swizzled 16B chunk within row
    int ta = rowtok[row0 + ar]; if (ta < 0) ta = 0;     // pad rows -> row 0 (discarded later)
    const short* ag  = A + (size_t)ta * K + achunk * 8;

    const short* be  = B + (size_t)e * Ntot * K + (size_t)n0 * K;
    const short* bg0 = be + (size_t)(((w * 2 + 0) << 4) + (l >> 2)) * K + achunk * 8;
    const short* bg1 = be + (size_t)(((w * 2 + 1) << 4) + (l >> 2)) * K + achunk * 8;

    // wave-uniform LDS destinations (base + lane*16 fills 16 rows x 64B)
    auto ldsA  = (__attribute__((address_space(3))) void*)&As[w << 4][0];
    auto ldsB0 = (__attribute__((address_space(3))) void*)&Bs[(w * 2 + 0) << 4][0];
    auto ldsB1 = (__attribute__((address_space(3))) void*)&Bs[(w * 2 + 1) << 4][0];

    // ---- fragment read addresses ----
    int mlane = l & 15, qlane = l >> 4;
    int rchunk = ((qlane ^ ((l >> 1) & 3)) << 3);   // swizzled chunk, in shorts
    int wm = w >> 1, wn = w & 1;                    // wave -> 32m x 64n sub-tile
    const short* pA0 = &As[wm * 32 + mlane][rchunk];
    const short* pA1 = pA0 + 16 * BK;
    const short* pB0 = &Bs[wn * 64 + mlane][rchunk];
    const short* pB1 = pB0 + 16 * BK;
    const short* pB2 = pB0 + 32 * BK;
    const short* pB3 = pB0 + 48 * BK;

    f32x4 acc[2][4] = {};

    for (int k0 = 0; k0 < K; k0 += BK) {
        GLD16(ag, ldsA);
        GLD16(bg0, ldsB0);
        GLD16(bg1, ldsB1);
        ag += BK; bg0 += BK; bg1 += BK;
        __syncthreads();   // drains vmcnt (global_load_lds) before reads

        short8 a0 = *(const short8*)pA0;
        short8 a1 = *(const short8*)pA1;
        short8 b0 = *(const short8*)pB0;
        short8 b1 = *(const short8*)pB1;
        short8 b2 = *(const short8*)pB2;
        short8 b3 = *(const short8*)pB3;

        acc[0][0] = __builtin_amdgcn_mfma_f32_16x16x32_bf16(a0, b0, acc[0][0], 0, 0, 0);
        acc[0][1] = __builtin_amdgcn_mfma_f32_16x16x32_bf16(a0, b1, acc[0][1], 0, 0, 0);
        acc[0][2] = __builtin_amdgcn_mfma_f32_16x16x32_bf16(a0, b2, acc[0][2], 0, 0, 0);
        acc[0][3] = __builtin_amdgcn_mfma_f32_16x16x32_bf16(a0, b3, acc[0][3], 0, 0, 0);
        acc[1][0] = __builtin_amdgcn_mfma_f32_16x16x32_bf16(a1, b0, acc[1][0], 0, 0, 0);
        acc[1][1] = __builtin_amdgcn_mfma_f32_16x16x32_bf16(a1, b1, acc[1][1], 0, 0, 0);
        acc[1][2] = __builtin_amdgcn_mfma_f32_16x16x32_bf16(a1, b2, acc[1][2], 0, 0, 0);
        acc[1][3] = __builtin_amdgcn_mfma_f32_16x16x32_bf16(a1, b3, acc[1][3], 0, 0, 0);
        __syncthreads();   // all reads done before next overwrite
    }

    // epilogue: D layout col = lane&15, row = (lane>>4)*4 + reg  [m89-verified]
#pragma unroll
    for (int i = 0; i < 2; i++) {
        int rbase = row0 + wm * 32 + i * 16 + qlane * 4;
#pragma unroll
        for (int j = 0; j < 4; j++) {
            int col = n0 + wn * 64 + j * 16 + mlane;
#pragma unroll
            for (int r = 0; r < 4; r++)
                C[(size_t)(rbase + r) * Ntot + col] = f2bf(acc[i][j][r]);
        }
    }
}

// ---------------------------------------------------------------------------
// Combine down rows -> per-token down (fp32 gates), emit bf16 for up GEMM.
// One block per token, 256 threads = DG elements.
// ---------------------------------------------------------------------------
__global__ __launch_bounds__(256) void combine1_kernel(const short* __restrict__ dr,
                                                       const int* __restrict__ rowpos,
                                                       const float* __restrict__ gval,
                                                       short* __restrict__ dt)
{
    int t = blockIdx.x, d = threadIdx.x;
    int   p0 = rowpos[2 * t], p1 = rowpos[2 * t + 1];
    float g0 = gval[2 * t],   g1 = gval[2 * t + 1];
    float v = g0 * b2f(dr[(size_t)p0 * DG + d]) + g1 * b2f(dr[(size_t)p1 * DG + d]);
    dt[(size_t)t * DG + d] = f2bf(v);
}

// ---------------------------------------------------------------------------
// Combine up rows -> final output (fp32). short4-vectorized.
// ---------------------------------------------------------------------------
__global__ __launch_bounds__(256) void combine2_kernel(const short* __restrict__ ur,
                                                       const int* __restrict__ rowpos,
                                                       const float* __restrict__ gval,
                                                       float* __restrict__ out)
{
    int i = blockIdx.x * 256 + threadIdx.x;       // i < T*D/4
    int t = i >> 9;                               // D/4 = 512
    int c = (i & 511) * 4;
    int   p0 = rowpos[2 * t], p1 = rowpos[2 * t + 1];
    float g0 = gval[2 * t],   g1 = gval[2 * t + 1];
    short4 u0 = *(const short4*)&ur[(size_t)p0 * DIM + c];
    short4 u1 = *(const short4*)&ur[(size_t)p1 * DIM + c];
    float4 o;
    o.x = g0 * b2f(u0.x) + g1 * b2f(u1.x);
    o.y = g0 * b2f(u0.y) + g1 * b2f(u1.y);
    o.z = g0 * b2f(u0.z) + g1 * b2f(u1.z);
    o.w = g0 * b2f(u0.w) + g1 * b2f(u1.w);
    *(float4*)&out[(size_t)t * DIM + c] = o;
}

// ---------------------------------------------------------------------------
// Workspace (bytes): ~76 MB total
// ---------------------------------------------------------------------------
extern "C" void kernel_launch(void* const* d_in, const int* in_sizes, int n_in,
                              void* d_out, int out_size, void* d_ws, size_t ws_size,
                              hipStream_t stream) {
    const float* x  = (const float*)d_in[0];
    const float* Wg = (const float*)d_in[1];
    const float* Wd = (const float*)d_in[2];
    const float* Wu = (const float*)d_in[3];
    float* out = (float*)d_out;

    char* p = (char*)d_ws;
    int*   gidx    = (int*)(p + 0);                       // 32768
    float* gval    = (float*)(p + 32768);                 // 32768
    int*   rowtok  = (int*)(p + 65536);                   // 34816
    int*   rowpos  = (int*)(p + 100352);                  // 32768
    int*   seg_off = (int*)(p + 133120);                  // 256 (padded)
    short* x_bf    = (short*)(p + 133376);                // 16777216
    short* Wd_bf   = (short*)(p + 133376 + 16777216);     // 8388608
    short* Wu_bf   = Wd_bf + 4194304;                     // 8388608
    short* dr_bf   = Wu_bf + 4194304;                     // NROWS*DG*2  = 4456448
    short* dt_bf   = dr_bf + (size_t)NROWS * DG;          // T*DG*2      = 2097152
    short* ur_bf   = dt_bf + (size_t)T_TOK * DG;          // NROWS*DIM*2 = 35651584

    conv_kernel<<<(T_TOK * DIM / 4 + 255) / 256, 256, 0, stream>>>(x, x_bf, T_TOK * DIM / 4);
    conv_kernel<<<(NEXP * DG * DIM / 4 + 255) / 256, 256, 0, stream>>>(Wd, Wd_bf, NEXP * DG * DIM / 4);
    conv_kernel<<<(NEXP * DIM * DG / 4 + 255) / 256, 256, 0, stream>>>(Wu, Wu_bf, NEXP * DIM * DG / 4);
    gate_kernel<<<T_TOK / 4, 256, 0, stream>>>(x, Wg, gidx, gval);
    bucket_kernel<<<1, 256, 0, stream>>>(gidx, rowtok, rowpos, seg_off);

    gemm_kernel<DIM, DG><<<dim3(NBLK_M, DG / BN), 256, 0, stream>>>(x_bf, Wd_bf, rowtok, seg_off, dr_bf);
    combine1_kernel<<<T_TOK, 256, 0, stream>>>(dr_bf, rowpos, gval, dt_bf);
    gemm_kernel<DG, DIM><<<dim3(NBLK_M, DIM / BN), 256, 0, stream>>>(dt_bf, Wu_bf, rowtok, seg_off, ur_bf);
    combine2_kernel<<<T_TOK * DIM / 4 / 256, 256, 0, stream>>>(ur_bf, rowpos, gval, out);
}

// Round 3
// 198.913 us; speedup vs baseline: 3.0937x; 1.3754x over previous
//
#include <hip/hip_runtime.h>
#include <hip/hip_bf16.h>
#include <stdint.h>

// Problem constants (B=2, L=2048, D=2048, E=8, Dg=256, k=2)
#define T_TOK 4096
#define DIM   2048
#define NEXP  8
#define DG    256
#define TOPK  2

// GEMM tiling: block tile 64(M) x 128(N), BK=32, 4 waves of 32x64 each
#define BM 64
#define BN 128
#define BK 32
#define NROWS  (T_TOK*TOPK + NEXP*BM)   // 8704 padded row capacity
#define NBLK_M (NROWS/BM)               // 136 M-blocks

typedef __attribute__((ext_vector_type(8))) short short8;
typedef __attribute__((ext_vector_type(4))) float f32x4;

static __device__ __forceinline__ short f2bf(float f) {
    union { float f; uint32_t u; } v{f};
    uint32_t r = v.u + 0x7fffu + ((v.u >> 16) & 1u);   // RNE
    return (short)(r >> 16);
}
static __device__ __forceinline__ float b2f(short s) {
    union { uint32_t u; float f; } v{((uint32_t)(unsigned short)s) << 16};
    return v.f;
}

#define GLD16(g, l) \
    __builtin_amdgcn_global_load_lds((const __attribute__((address_space(1))) void*)(g), \
                                     (__attribute__((address_space(3))) void*)(l), 16, 0, 0)

// ---------------------------------------------------------------------------
// Gate + x->bf16 fusion. One wave per token.
// Lane holds 32 x elements (8 x float4); 8 per-expert accumulators; ONE
// interleaved 6-level butterfly (8 independent chains pipeline).
// Also emits x_bf (coalesced short4 stores) for the down GEMM.
// ---------------------------------------------------------------------------
__global__ __launch_bounds__(256) void gate_kernel(const float* __restrict__ x,
                                                   const float* __restrict__ Wg,
                                                   int* __restrict__ gidx,
                                                   float* __restrict__ gval,
                                                   short* __restrict__ x_bf)
{
    int token = blockIdx.x * 4 + (threadIdx.x >> 6);
    int lane  = threadIdx.x & 63;
    const float4* xr = (const float4*)(x + (size_t)token * DIM);

    float4 xv[8];
#pragma unroll
    for (int i = 0; i < 8; i++) xv[i] = xr[lane + 64 * i];

    // fused bf16 emit (coalesced: 64 lanes x 8B)
    short4* xb = (short4*)(x_bf + (size_t)token * DIM);
#pragma unroll
    for (int i = 0; i < 8; i++) {
        short4 o;
        o.x = f2bf(xv[i].x); o.y = f2bf(xv[i].y);
        o.z = f2bf(xv[i].z); o.w = f2bf(xv[i].w);
        xb[lane + 64 * i] = o;
    }

    float acc[NEXP];
#pragma unroll
    for (int e = 0; e < NEXP; e++) {
        const float4* wr = (const float4*)(Wg + e * DIM);
        float a = 0.0f;
#pragma unroll
        for (int i = 0; i < 8; i++) {
            float4 w = wr[lane + 64 * i];
            a += xv[i].x * w.x + xv[i].y * w.y + xv[i].z * w.z + xv[i].w * w.w;
        }
        acc[e] = a;
    }

    // interleaved butterfly: 6 levels, 8 independent chains
#pragma unroll
    for (int m = 1; m < 64; m <<= 1) {
#pragma unroll
        for (int e = 0; e < NEXP; e++) acc[e] += __shfl_xor(acc[e], m, 64);
    }

    if (lane == 0) {
        float sg[NEXP];
#pragma unroll
        for (int e = 0; e < NEXP; e++) sg[e] = 1.0f / (1.0f + expf(-acc[e]));
        int i0 = 0;
#pragma unroll
        for (int e = 1; e < NEXP; e++) if (sg[e] > sg[i0]) i0 = e;   // strict >: lowest index wins
        int i1 = (i0 == 0) ? 1 : 0;
#pragma unroll
        for (int e = 0; e < NEXP; e++) if (e != i0 && e != i1 && sg[e] > sg[i1]) i1 = e;
        gidx[2 * token + 0] = i0;
        gidx[2 * token + 1] = i1;
        gval[2 * token + 0] = sg[i0];
        gval[2 * token + 1] = sg[i1];
    }
}

// ---------------------------------------------------------------------------
// Weight fp32 -> bf16 (Wd and Wu in one launch). n4 elements of float4 each.
// ---------------------------------------------------------------------------
__global__ __launch_bounds__(256) void convW_kernel(const float* __restrict__ Wd,
                                                    const float* __restrict__ Wu,
                                                    short* __restrict__ Wd_bf,
                                                    short* __restrict__ Wu_bf,
                                                    int n4)
{
    int i = blockIdx.x * 256 + threadIdx.x;
    const float* s; short* d; int j;
    if (i < n4)      { s = Wd; d = Wd_bf; j = i; }
    else             { s = Wu; d = Wu_bf; j = i - n4; if (j >= n4) return; }
    float4 v = ((const float4*)s)[j];
    short4 o;
    o.x = f2bf(v.x); o.y = f2bf(v.y); o.z = f2bf(v.z); o.w = f2bf(v.w);
    ((short4*)d)[j] = o;
}

// ---------------------------------------------------------------------------
// Bucket rows by expert (segments padded to BM); forward map rowtok and
// inverse map rowpos[2t+s]. Single block, 1024 threads.
// ---------------------------------------------------------------------------
__global__ __launch_bounds__(1024) void bucket_kernel(const int* __restrict__ gidx,
                                                      int* __restrict__ rowtok,
                                                      int* __restrict__ rowpos,
                                                      int* __restrict__ seg_off)
{
    __shared__ int cnt[NEXP];
    __shared__ int cur[NEXP];
    int tid = threadIdx.x;
    if (tid < NEXP) cnt[tid] = 0;
    __syncthreads();

    for (int t = tid; t < T_TOK; t += 1024) {
        atomicAdd(&cnt[gidx[2 * t + 0]], 1);
        atomicAdd(&cnt[gidx[2 * t + 1]], 1);
    }
    __syncthreads();

    if (tid == 0) {
        int o = 0;
        for (int e = 0; e < NEXP; e++) {
            seg_off[e] = o;
            cur[e] = o;
            o += ((cnt[e] + BM - 1) / BM) * BM;
        }
        seg_off[NEXP] = o;
    }
    __syncthreads();

    for (int r = tid; r < NROWS; r += 1024) rowtok[r] = -1;
    __syncthreads();

    for (int t = tid; t < T_TOK; t += 1024) {
        for (int s = 0; s < TOPK; s++) {
            int e = gidx[2 * t + s];
            int p = atomicAdd(&cur[e], 1);
            rowtok[p] = t;
            rowpos[2 * t + s] = p;
        }
    }
}

// ---------------------------------------------------------------------------
// Grouped GEMM (bf16 MFMA): C[row][n] = sum_k A[rowtok[row]][k] * B[e][n][k]
// Staging via global_load_lds width=16 (per-lane global addr, wave-uniform
// LDS base). 16B-chunk XOR swizzle keeps ds_read_b128 fragment reads 2-way.
// ---------------------------------------------------------------------------
template<int K, int Ntot>
__global__ __launch_bounds__(256) void gemm_kernel(const short* __restrict__ A,
                                                   const short* __restrict__ B,
                                                   const int* __restrict__ rowtok,
                                                   const int* __restrict__ seg_off,
                                                   short* __restrict__ C)
{
    __shared__ short As[BM][BK];   // 4 KB
    __shared__ short Bs[BN][BK];   // 8 KB

    int row0 = blockIdx.x * BM;
    int total = seg_off[NEXP];
    if (row0 >= total) return;
    int e = 0;
    while (row0 >= seg_off[e + 1]) ++e;   // BM-padded segments: block in one expert
    int n0 = blockIdx.y * BN;

    int tid = threadIdx.x;
    int w = tid >> 6, l = tid & 63;

    // ---- staging addresses ----
    int ar = (w << 4) + (l >> 2);
    int achunk = (l & 3) ^ ((l >> 3) & 3);
    int ta = rowtok[row0 + ar]; if (ta < 0) ta = 0;
    const short* ag  = A + (size_t)ta * K + achunk * 8;

    const short* be  = B + (size_t)e * Ntot * K + (size_t)n0 * K;
    const short* bg0 = be + (size_t)(((w * 2 + 0) << 4) + (l >> 2)) * K + achunk * 8;
    const short* bg1 = be + (size_t)(((w * 2 + 1) << 4) + (l >> 2)) * K + achunk * 8;

    auto ldsA  = (__attribute__((address_space(3))) void*)&As[w << 4][0];
    auto ldsB0 = (__attribute__((address_space(3))) void*)&Bs[(w * 2 + 0) << 4][0];
    auto ldsB1 = (__attribute__((address_space(3))) void*)&Bs[(w * 2 + 1) << 4][0];

    // ---- fragment read addresses ----
    int mlane = l & 15, qlane = l >> 4;
    int rchunk = ((qlane ^ ((l >> 1) & 3)) << 3);
    int wm = w >> 1, wn = w & 1;
    const short* pA0 = &As[wm * 32 + mlane][rchunk];
    const short* pA1 = pA0 + 16 * BK;
    const short* pB0 = &Bs[wn * 64 + mlane][rchunk];
    const short* pB1 = pB0 + 16 * BK;
    const short* pB2 = pB0 + 32 * BK;
    const short* pB3 = pB0 + 48 * BK;

    f32x4 acc[2][4] = {};

    for (int k0 = 0; k0 < K; k0 += BK) {
        GLD16(ag, ldsA);
        GLD16(bg0, ldsB0);
        GLD16(bg1, ldsB1);
        ag += BK; bg0 += BK; bg1 += BK;
        __syncthreads();

        short8 a0 = *(const short8*)pA0;
        short8 a1 = *(const short8*)pA1;
        short8 b0 = *(const short8*)pB0;
        short8 b1 = *(const short8*)pB1;
        short8 b2 = *(const short8*)pB2;
        short8 b3 = *(const short8*)pB3;

        acc[0][0] = __builtin_amdgcn_mfma_f32_16x16x32_bf16(a0, b0, acc[0][0], 0, 0, 0);
        acc[0][1] = __builtin_amdgcn_mfma_f32_16x16x32_bf16(a0, b1, acc[0][1], 0, 0, 0);
        acc[0][2] = __builtin_amdgcn_mfma_f32_16x16x32_bf16(a0, b2, acc[0][2], 0, 0, 0);
        acc[0][3] = __builtin_amdgcn_mfma_f32_16x16x32_bf16(a0, b3, acc[0][3], 0, 0, 0);
        acc[1][0] = __builtin_amdgcn_mfma_f32_16x16x32_bf16(a1, b0, acc[1][0], 0, 0, 0);
        acc[1][1] = __builtin_amdgcn_mfma_f32_16x16x32_bf16(a1, b1, acc[1][1], 0, 0, 0);
        acc[1][2] = __builtin_amdgcn_mfma_f32_16x16x32_bf16(a1, b2, acc[1][2], 0, 0, 0);
        acc[1][3] = __builtin_amdgcn_mfma_f32_16x16x32_bf16(a1, b3, acc[1][3], 0, 0, 0);
        __syncthreads();
    }

    // epilogue: D layout col = lane&15, row = (lane>>4)*4 + reg  [m89-verified]
#pragma unroll
    for (int i = 0; i < 2; i++) {
        int rbase = row0 + wm * 32 + i * 16 + qlane * 4;
#pragma unroll
        for (int j = 0; j < 4; j++) {
            int col = n0 + wn * 64 + j * 16 + mlane;
#pragma unroll
            for (int r = 0; r < 4; r++)
                C[(size_t)(rbase + r) * Ntot + col] = f2bf(acc[i][j][r]);
        }
    }
}

// ---------------------------------------------------------------------------
// Combine down rows -> per-token down (fp32 gates), emit bf16 for up GEMM.
// ---------------------------------------------------------------------------
__global__ __launch_bounds__(256) void combine1_kernel(const short* __restrict__ dr,
                                                       const int* __restrict__ rowpos,
                                                       const float* __restrict__ gval,
                                                       short* __restrict__ dt)
{
    int t = blockIdx.x, d = threadIdx.x;
    int   p0 = rowpos[2 * t], p1 = rowpos[2 * t + 1];
    float g0 = gval[2 * t],   g1 = gval[2 * t + 1];
    float v = g0 * b2f(dr[(size_t)p0 * DG + d]) + g1 * b2f(dr[(size_t)p1 * DG + d]);
    dt[(size_t)t * DG + d] = f2bf(v);
}

// ---------------------------------------------------------------------------
// Combine up rows -> final output (fp32). short4-vectorized.
// ---------------------------------------------------------------------------
__global__ __launch_bounds__(256) void combine2_kernel(const short* __restrict__ ur,
                                                       const int* __restrict__ rowpos,
                                                       const float* __restrict__ gval,
                                                       float* __restrict__ out)
{
    int i = blockIdx.x * 256 + threadIdx.x;       // i < T*D/4
    int t = i >> 9;                               // D/4 = 512
    int c = (i & 511) * 4;
    int   p0 = rowpos[2 * t], p1 = rowpos[2 * t + 1];
    float g0 = gval[2 * t],   g1 = gval[2 * t + 1];
    short4 u0 = *(const short4*)&ur[(size_t)p0 * DIM + c];
    short4 u1 = *(const short4*)&ur[(size_t)p1 * DIM + c];
    float4 o;
    o.x = g0 * b2f(u0.x) + g1 * b2f(u1.x);
    o.y = g0 * b2f(u0.y) + g1 * b2f(u1.y);
    o.z = g0 * b2f(u0.z) + g1 * b2f(u1.z);
    o.w = g0 * b2f(u0.w) + g1 * b2f(u1.w);
    *(float4*)&out[(size_t)t * DIM + c] = o;
}

extern "C" void kernel_launch(void* const* d_in, const int* in_sizes, int n_in,
                              void* d_out, int out_size, void* d_ws, size_t ws_size,
                              hipStream_t stream) {
    const float* x  = (const float*)d_in[0];
    const float* Wg = (const float*)d_in[1];
    const float* Wd = (const float*)d_in[2];
    const float* Wu = (const float*)d_in[3];
    float* out = (float*)d_out;

    char* p = (char*)d_ws;
    int*   gidx    = (int*)(p + 0);                       // 32768
    float* gval    = (float*)(p + 32768);                 // 32768
    int*   rowtok  = (int*)(p + 65536);                   // 34816
    int*   rowpos  = (int*)(p + 100352);                  // 32768
    int*   seg_off = (int*)(p + 133120);                  // 256 (padded)
    short* x_bf    = (short*)(p + 133376);                // 16777216
    short* Wd_bf   = (short*)(p + 133376 + 16777216);     // 8388608
    short* Wu_bf   = Wd_bf + 4194304;                     // 8388608
    short* dr_bf   = Wu_bf + 4194304;                     // NROWS*DG*2  = 4456448
    short* dt_bf   = dr_bf + (size_t)NROWS * DG;          // T*DG*2      = 2097152
    short* ur_bf   = dt_bf + (size_t)T_TOK * DG;          // NROWS*DIM*2 = 35651584

    const int W4 = NEXP * DG * DIM / 4;   // 1048576 float4 per weight tensor
    gate_kernel<<<T_TOK / 4, 256, 0, stream>>>(x, Wg, gidx, gval, x_bf);
    convW_kernel<<<(2 * W4 + 255) / 256, 256, 0, stream>>>(Wd, Wu, Wd_bf, Wu_bf, W4);
    bucket_kernel<<<1, 1024, 0, stream>>>(gidx, rowtok, rowpos, seg_off);

    gemm_kernel<DIM, DG><<<dim3(NBLK_M, DG / BN), 256, 0, stream>>>(x_bf, Wd_bf, rowtok, seg_off, dr_bf);
    combine1_kernel<<<T_TOK, 256, 0, stream>>>(dr_bf, rowpos, gval, dt_bf);
    gemm_kernel<DG, DIM><<<dim3(NBLK_M, DIM / BN), 256, 0, stream>>>(dt_bf, Wu_bf, rowtok, seg_off, ur_bf);
    combine2_kernel<<<T_TOK * DIM / 4 / 256, 256, 0, stream>>>(ur_bf, rowpos, gval, out);
}